// Round 7
// baseline (4280.993 us; speedup 1.0000x reference)
//
#include <hip/hip_runtime.h>

// GraphSAGE (2x SAGEConv mean + global_mean_pool) on MI355X.
// R6: shard-aligned edge-centric aggregation. R5 profile: agg1 FETCH 350MB
// (gather of 819MB logical from a 25.6MB table, random src -> ~16% L2 hit).
// Fix: edges partitioned per 128-dst tile, then counting-sorted by src-shard
// (src>>12, 25 shards x 1MB of xh). One block per tile accumulates its edges
// into a 64KB LDS fp32 tile; all blocks walk equal-length shard-sorted lists
// in lockstep -> at any instant all CUs gather from the same 1-2MB shard ->
// L2-resident. Replaces csr/offs/bbuild entirely (agg2 reuses sorted edges +
// invdeg from agg1). LDS accum uses split layout (ch 2k->word k, 2k+1->64+k)
// so ds_add_f32 is 2 lanes/bank = conflict-free.

constexpr int NN = 100000;    // nodes
constexpr int NE = 3200000;   // edges
constexpr int C1 = 128;       // IN_C == HID_C
constexpr int C2 = 64;        // OUT_C
constexpr int NG = 1024;      // graphs

constexpr int NT   = (NN + 127) >> 7;   // 782 dst tiles of 128 nodes
constexpr int NSH  = 25;                // src shards (src>>12), 4096 nodes = 1MB xh
constexpr int SCAP = 6144;              // ssort LDS cap (mean 4096, std 64)

typedef unsigned int u32;
typedef unsigned short u16;
typedef _Float16 f16;
typedef f16 f16x8 __attribute__((ext_vector_type(8)));
typedef float f32x4 __attribute__((ext_vector_type(4)));

__device__ __forceinline__ float h2f(u32 bits16) {
  f16 h; u16 b = (u16)bits16;
  __builtin_memcpy(&h, &b, 2);
  return (float)h;
}
__device__ __forceinline__ u16 f2h(float f) {
  f16 h = (f16)f; u16 b;
  __builtin_memcpy(&b, &h, 2);
  return b;
}
__device__ __forceinline__ u32 packh2(float a, float b) {
  return (u32)f2h(a) | ((u32)f2h(b) << 16);
}

// ---------------- x -> fp16 ----------------
__global__ __launch_bounds__(256)
void sage_x2h(const float* __restrict__ x, u16* __restrict__ xh) {
  const int i = blockIdx.x * 256 + threadIdx.x;       // one float4 per thread
  if (i >= NN * C1 / 4) return;
  const float4 v = ((const float4*)x)[i];
  uint2 o;
  o.x = packh2(v.x, v.y);
  o.y = packh2(v.z, v.w);
  ((uint2*)xh)[i] = o;
}

// ------------- weights -> fp16, transposed [N][K] -------------
__global__ __launch_bounds__(256)
void sage_wprep(const float* __restrict__ W1l, const float* __restrict__ W1r,
                const float* __restrict__ W2l, const float* __restrict__ W2r,
                u16* __restrict__ wt1, u16* __restrict__ wt2) {
  const int id = blockIdx.x * 256 + threadIdx.x;
  if (id < 128 * 256) {
    const int n = id >> 8, k = id & 255;
    const float v = (k < 128) ? W1l[k * 128 + n] : W1r[(k - 128) * 128 + n];
    wt1[id] = f2h(v);
  } else if (id < 128 * 256 + 128 * 128) {
    const int id2 = id - 128 * 256;
    const int n = id2 >> 7, k = id2 & 127;
    const float v = (n < 64) ? W2l[k * 64 + n] : W2r[k * 64 + (n - 64)];
    wt2[id2] = f2h(v);
  }
}

// ---------------- edge partition by dst tile (128 nodes) ----------------
__global__ __launch_bounds__(256)
void sage_phist(const int* __restrict__ edst, int* __restrict__ thist) {
  __shared__ int h[NT];
  for (int i = threadIdx.x; i < NT; i += 256) h[i] = 0;
  __syncthreads();
  const int e0 = blockIdx.x * 4096 + threadIdx.x;
#pragma unroll
  for (int j = 0; j < 16; ++j) {
    const int e = e0 + j * 256;
    if (e < NE) atomicAdd(&h[edst[e] >> 7], 1);
  }
  __syncthreads();
  for (int i = threadIdx.x; i < NT; i += 256)
    if (h[i]) atomicAdd(&thist[i], h[i]);
}

// exclusive scan of NT tile counts -> tbase[NT+1] (and seed gcur).
__global__ __launch_bounds__(256)
void sage_pscan(const int* __restrict__ thist, int* __restrict__ tbase,
                int* __restrict__ gcur) {
  __shared__ int s[256];
  const int t = threadIdx.x;
  int v[4], sum = 0;
#pragma unroll
  for (int j = 0; j < 4; ++j) {
    const int idx = t * 4 + j;
    v[j] = (idx < NT) ? thist[idx] : 0;
    sum += v[j];
  }
  s[t] = sum;
  __syncthreads();
  for (int d = 1; d < 256; d <<= 1) {
    const int a = (t >= d) ? s[t - d] : 0;
    __syncthreads();
    s[t] += a;
    __syncthreads();
  }
  int run = s[t] - sum;                               // exclusive over threads
#pragma unroll
  for (int j = 0; j < 4; ++j) {
    const int idx = t * 4 + j;
    if (idx <= NT) tbase[idx] = run;
    if (idx < NT) { gcur[idx] = run; run += v[j]; }
  }
}

// partition edges into tile-contiguous runs of packed (src<<7)|(dst&127).
__global__ __launch_bounds__(256)
void sage_part(const int* __restrict__ esrc, const int* __restrict__ edst,
               int* __restrict__ gcur, u32* __restrict__ gpart) {
  __shared__ int h[NT], cur[NT];
  for (int i = threadIdx.x; i < NT; i += 256) h[i] = 0;
  __syncthreads();
  const int e0 = blockIdx.x * 4096 + threadIdx.x;
#pragma unroll
  for (int j = 0; j < 16; ++j) {
    const int e = e0 + j * 256;
    if (e < NE) atomicAdd(&h[edst[e] >> 7], 1);
  }
  __syncthreads();
  for (int i = threadIdx.x; i < NT; i += 256)
    cur[i] = h[i] ? atomicAdd(&gcur[i], h[i]) : 0;
  __syncthreads();
#pragma unroll
  for (int j = 0; j < 16; ++j) {
    const int e = e0 + j * 256;
    if (e < NE) {
      const int d = edst[e];
      const int p = atomicAdd(&cur[d >> 7], 1);
      gpart[p] = ((u32)esrc[e] << 7) | (u32)(d & 127);
    }
  }
}

// per-tile counting sort by src shard (pk>>19, 25 bins) -> gpart2.
// Cap SCAP (+32 sigma); over-cap tiles copy through unsorted (still correct).
__global__ __launch_bounds__(256)
void sage_ssort(const int* __restrict__ tbase, const u32* __restrict__ gpart,
                u32* __restrict__ gpart2) {
  __shared__ u32 ebuf[SCAP];
  __shared__ int hcur[NSH];
  const int b = blockIdx.x, t = threadIdx.x;
  const int tb = tbase[b], cnt = tbase[b + 1] - tb;
  if (cnt > SCAP) {                                   // statistical fallback
    for (int e = t; e < cnt; e += 256) gpart2[tb + e] = gpart[tb + e];
    return;
  }
  __shared__ int h[NSH];
  if (t < NSH) h[t] = 0;
  __syncthreads();
  for (int e = t; e < cnt; e += 256) {
    const u32 pk = gpart[tb + e];
    ebuf[e] = pk;
    atomicAdd(&h[pk >> 19], 1);
  }
  __syncthreads();
  if (t == 0) {
    int run = 0;
    for (int i = 0; i < NSH; ++i) { hcur[i] = run; run += h[i]; }
  }
  __syncthreads();
  for (int e = t; e < cnt; e += 256) {
    const u32 pk = ebuf[e];
    const int p = atomicAdd(&hcur[pk >> 19], 1);
    gpart2[tb + p] = pk;
  }
}

// ------------- edge-centric aggregation 1: mean of xh over in-edges -------
// Block per dst tile (128 nodes). LDS accum 128x128 fp32, split layout:
// channel 2k -> word k, channel 2k+1 -> word 64+k (ds_add 2 lanes/bank).
// Wave per edge (64 lanes x u32 = the 256B xh row), 4 edges/wave/iter.
__global__ __launch_bounds__(256)
void sage_eagg1(const int* __restrict__ tbase, const u32* __restrict__ gpart2,
                const u16* __restrict__ xh, u16* __restrict__ aggh,
                float* __restrict__ invdeg) {
  __shared__ float acc[128 * 128];
  __shared__ int cnt[128];
  const int t = threadIdx.x;
  for (int i = t; i < 128 * 128; i += 256) acc[i] = 0.f;
  if (t < 128) cnt[t] = 0;
  __syncthreads();
  const int b = blockIdx.x;
  const int tb = tbase[b], te = tbase[b + 1];
  const int w = t >> 6, lane = t & 63;
  for (int e0 = tb + w * 4; e0 < te; e0 += 16) {
#pragma unroll
    for (int j = 0; j < 4; ++j) {
      const int e = e0 + j;
      if (e < te) {
        const u32 pk = gpart2[e];
        const int src = pk >> 7, d = pk & 127;
        const u32 g = *(const u32*)(xh + (size_t)src * 128 + lane * 2);
        atomicAdd(&acc[d * 128 + lane], h2f(g & 0xffffu));        // ch 2*lane
        atomicAdd(&acc[d * 128 + 64 + lane], h2f(g >> 16));       // ch 2*lane+1
        if (lane == 0) atomicAdd(&cnt[d], 1);
      }
    }
  }
  __syncthreads();
  for (int i = t; i < 128 * 64; i += 256) {           // row-major fp16 out
    const int row = i >> 6, k = i & 63;
    const int node = b * 128 + row;
    if (node < NN) {
      const float inv = 1.0f / fmaxf((float)cnt[row], 1.0f);
      const u32 o = packh2(acc[row * 128 + k] * inv, acc[row * 128 + 64 + k] * inv);
      ((u32*)aggh)[(size_t)node * 64 + k] = o;
      if (k == 0) invdeg[node] = inv;
    }
  }
}

// ------------- edge-centric aggregation 2: mean of t over in-edges -------
// t = cols 0..63 of o128 (first 128B of each 256B row). Half-wave per edge
// (32 lanes x u32), 8 edges/wave/iter. LDS accum 128x64 fp32 split layout.
__global__ __launch_bounds__(256)
void sage_eagg2(const int* __restrict__ tbase, const u32* __restrict__ gpart2,
                const u16* __restrict__ o128, const float* __restrict__ invdeg,
                float* __restrict__ agg) {
  __shared__ float acc[128 * 64];
  const int t = threadIdx.x;
  for (int i = t; i < 128 * 64; i += 256) acc[i] = 0.f;
  __syncthreads();
  const int b = blockIdx.x;
  const int tb = tbase[b], te = tbase[b + 1];
  const int w = t >> 6, lane = t & 63;
  const int hf = lane >> 5, l = lane & 31;
  for (int e0 = tb + w * 8; e0 < te; e0 += 32) {
#pragma unroll
    for (int j = 0; j < 4; ++j) {
      const int e = e0 + j * 2 + hf;
      if (e < te) {
        const u32 pk = gpart2[e];
        const int src = pk >> 7, d = pk & 127;
        const u32 g = *(const u32*)(o128 + (size_t)src * 128 + l * 2);
        atomicAdd(&acc[d * 64 + l], h2f(g & 0xffffu));            // ch 2l
        atomicAdd(&acc[d * 64 + 32 + l], h2f(g >> 16));           // ch 2l+1
      }
    }
  }
  __syncthreads();
  for (int i = t; i < 128 * 64; i += 256) {
    const int row = i >> 6, c = i & 63;
    const int node = b * 128 + row;
    if (node < NN)
      agg[(size_t)node * 64 + c] =
          acc[row * 64 + (c >> 1) + (c & 1) * 32] * invdeg[node];
  }
}

// ------------- MFMA GEMM 1: H = relu(A1@W1l + A2@W1r + b1), fp16 out -------
__global__ __launch_bounds__(256)
void sage_mgemm1(const u16* __restrict__ A1, const u16* __restrict__ A2,
                 const u16* __restrict__ wt1, const float* __restrict__ bias,
                 u16* __restrict__ H) {
  __shared__ __align__(16) u16 As[2][64][128];
  const int t = threadIdx.x;
  const int r0 = blockIdx.x * 64;
#pragma unroll
  for (int i = 0; i < 8; ++i) {                       // 2048 16B-chunk loads
    const int id = i * 256 + t;
    const int buf = id >> 10;
    const int id2 = id & 1023;
    const int row = id2 >> 4, c = id2 & 15;
    int gr = r0 + row; gr = (gr < NN) ? gr : NN - 1;  // clamp; store guarded
    const uint4 v = *(const uint4*)((buf ? A2 : A1) + (size_t)gr * 128 + c * 8);
    *(uint4*)(&As[buf][row][(c ^ (row & 7)) * 8]) = v;
  }
  __syncthreads();
  const int w = t >> 6, l = t & 63;
  const int lr = l & 15, lk = l >> 4;
  const int rowl = w * 16 + lr;
  f32x4 acc[8];
#pragma unroll
  for (int c = 0; c < 8; ++c) acc[c] = (f32x4){0.f, 0.f, 0.f, 0.f};
#pragma unroll
  for (int kt = 0; kt < 8; ++kt) {                    // K = 256 in 32-steps
    const int buf = kt >> 2, kk = kt & 3;
    const int ch = (kk * 4 + lk) ^ (rowl & 7);
    const f16x8 a = *(const f16x8*)(&As[buf][rowl][ch * 8]);
#pragma unroll
    for (int c = 0; c < 8; ++c) {
      const f16x8 b = *(const f16x8*)(wt1 + ((c * 16 + lr) * 256 + kt * 32 + lk * 8));
      acc[c] = __builtin_amdgcn_mfma_f32_16x16x32_f16(a, b, acc[c], 0, 0, 0);
    }
  }
#pragma unroll
  for (int c = 0; c < 8; ++c) {                       // C/D: col=l&15, row=lk*4+j
    const int col = c * 16 + lr;
    const float bv = bias[col];
#pragma unroll
    for (int j = 0; j < 4; ++j) {
      const int row = r0 + w * 16 + lk * 4 + j;
      if (row < NN) H[(size_t)row * 128 + col] = f2h(fmaxf(acc[c][j] + bv, 0.f));
    }
  }
}

// ------------- MFMA GEMM 2: O = H @ [W2l | W2r], fp16 out [NN][128] -------
__global__ __launch_bounds__(256)
void sage_mgemm2(const u16* __restrict__ A, const u16* __restrict__ wt2,
                 u16* __restrict__ O) {
  __shared__ __align__(16) u16 As[64][128];
  const int t = threadIdx.x;
  const int r0 = blockIdx.x * 64;
#pragma unroll
  for (int i = 0; i < 4; ++i) {
    const int id = i * 256 + t;
    const int row = id >> 4, c = id & 15;
    int gr = r0 + row; gr = (gr < NN) ? gr : NN - 1;
    const uint4 v = *(const uint4*)(A + (size_t)gr * 128 + c * 8);
    *(uint4*)(&As[row][(c ^ (row & 7)) * 8]) = v;
  }
  __syncthreads();
  const int w = t >> 6, l = t & 63;
  const int lr = l & 15, lk = l >> 4;
  const int rowl = w * 16 + lr;
  f32x4 acc[8];
#pragma unroll
  for (int c = 0; c < 8; ++c) acc[c] = (f32x4){0.f, 0.f, 0.f, 0.f};
#pragma unroll
  for (int kt = 0; kt < 4; ++kt) {                    // K = 128
    const int ch = (kt * 4 + lk) ^ (rowl & 7);
    const f16x8 a = *(const f16x8*)(&As[rowl][ch * 8]);
#pragma unroll
    for (int c = 0; c < 8; ++c) {
      const f16x8 b = *(const f16x8*)(wt2 + ((c * 16 + lr) * 128 + kt * 32 + lk * 8));
      acc[c] = __builtin_amdgcn_mfma_f32_16x16x32_f16(a, b, acc[c], 0, 0, 0);
    }
  }
#pragma unroll
  for (int c = 0; c < 8; ++c) {
    const int col = c * 16 + lr;
#pragma unroll
    for (int j = 0; j < 4; ++j) {
      const int row = r0 + w * 16 + lk * 4 + j;
      if (row < NN) O[(size_t)row * 128 + col] = f2h(acc[c][j]);
    }
  }
}

// ------------- pooling -------------
__global__ __launch_bounds__(256)
void sage_gcnt(const int* __restrict__ batch, int* __restrict__ gcnt) {
  const int n = blockIdx.x * 256 + threadIdx.x;
  if (n < NN) atomicAdd(&gcnt[batch[n]], 1);
}

// batch sorted: accumulate runs locally, one atomic per graph change.
__global__ __launch_bounds__(256)
void sage_pool2(const u16* __restrict__ o128, const float* __restrict__ agg2,
                const float* __restrict__ b2, const int* __restrict__ batch,
                float* __restrict__ pool) {
  const int t = threadIdx.x;
  const int c = t & 63, sl = t >> 6;
  const int n0 = blockIdx.x * 128;
  const float bv = b2[c];
  float acc = 0.f;
  int curg = -1;
  for (int n = n0 + sl; n < n0 + 128 && n < NN; n += 4) {
    const int g = batch[n];
    const float v = h2f(o128[(size_t)n * 128 + 64 + c]) + agg2[n * C2 + c] + bv;
    if (g != curg) {
      if (curg >= 0) atomicAdd(&pool[curg * C2 + c], acc);
      curg = g;
      acc = v;
    } else {
      acc += v;
    }
  }
  if (curg >= 0) atomicAdd(&pool[curg * C2 + c], acc);
}

__global__ __launch_bounds__(256)
void sage_out(const float* __restrict__ pool, const int* __restrict__ gcnt,
              float* __restrict__ out) {
  const int i = blockIdx.x * 256 + threadIdx.x;
  if (i >= NG * C2) return;
  out[i] = pool[i] / fmaxf((float)gcnt[i >> 6], 1.0f);
}

extern "C" void kernel_launch(void* const* d_in, const int* in_sizes, int n_in,
                              void* d_out, int out_size, void* d_ws, size_t ws_size,
                              hipStream_t stream) {
  (void)in_sizes; (void)n_in; (void)out_size; (void)ws_size;
  const float* x     = (const float*)d_in[0];
  const float* W1l   = (const float*)d_in[1];
  const float* b1    = (const float*)d_in[2];
  const float* W1r   = (const float*)d_in[3];
  const float* W2l   = (const float*)d_in[4];
  const float* b2    = (const float*)d_in[5];
  const float* W2r   = (const float*)d_in[6];
  const int*   ei    = (const int*)d_in[7];   // [2, NE]: row0 = src, row1 = dst
  const int*   batch = (const int*)d_in[8];
  const int* esrc = ei;
  const int* edst = ei + NE;
  float* out = (float*)d_out;

  // ---- workspace carve-out (~91 MB) ----
  char* base = (char*)d_ws;
  size_t off = 0;
  auto take = [&](size_t bytes) -> char* {
    char* p = base + off;
    off += (bytes + 255) & ~(size_t)255;
    return p;
  };
  int* thist    = (int*)take((size_t)NT * 4);
  int* tbase    = (int*)take((size_t)(NT + 1) * 4);
  int* gcur     = (int*)take((size_t)NT * 4);
  u32* gpart2   = (u32*)take((size_t)NE * 4);         // sorted edges (alive to eagg2)
  char* bufA    = take((size_t)NN * 256);   // xh (f16 NNx128) -> o128 (f16 NNx128)
  char* bufB    = take((size_t)NN * 256);   // agg1h (f16) -> agg2 (f32 NNx64)
  char* bufC    = take((size_t)NN * 256);   // gpart (u32 NE) -> hb (f16 NNx128)
  float* invdeg = (float*)take((size_t)NN * 4);
  float* pool   = (float*)take((size_t)NG * C2 * 4);
  int*  gcnt    = (int*)take((size_t)NG * 4);
  u16*  wt1     = (u16*)take((size_t)128 * 256 * 2);
  u16*  wt2     = (u16*)take((size_t)128 * 128 * 2);

  u16*   xh    = (u16*)bufA;
  u16*   o128  = (u16*)bufA;                // gemm2 out (xh dead by then)
  u16*   agg1h = (u16*)bufB;
  float* agg2  = (float*)bufB;
  u32*   gpart = (u32*)bufC;                // dead after ssort
  u16*   hb    = (u16*)bufC;                // written by mgemm1 after that

  hipMemsetAsync(thist, 0, (size_t)NT * 4, stream);
  hipMemsetAsync(pool, 0, (size_t)NG * C2 * 4, stream);
  hipMemsetAsync(gcnt, 0, (size_t)NG * 4, stream);

  sage_wprep<<<192, 256, 0, stream>>>(W1l, W1r, W2l, W2r, wt1, wt2);
  sage_x2h<<<(NN * C1 / 4 + 255) / 256, 256, 0, stream>>>(x, xh);

  // edge partition + shard sort
  const int PB = (NE + 4095) / 4096;        // 782 chunks
  sage_phist<<<PB, 256, 0, stream>>>(edst, thist);
  sage_pscan<<<1, 256, 0, stream>>>(thist, tbase, gcur);
  sage_part<<<PB, 256, 0, stream>>>(esrc, edst, gcur, gpart);
  sage_ssort<<<NT, 256, 0, stream>>>(tbase, gpart, gpart2);

  // layer 1
  sage_eagg1<<<NT, 256, 0, stream>>>(tbase, gpart2, xh, agg1h, invdeg);
  sage_mgemm1<<<(NN + 63) / 64, 256, 0, stream>>>(agg1h, xh, wt1, b1, hb);

  // layer 2 (transform-then-aggregate: mean(h)@W2l == mean(h@W2l));
  // o128 = h @ [W2l | W2r]  (cols 0..63 = t, 64..127 = t2)
  sage_mgemm2<<<(NN + 63) / 64, 256, 0, stream>>>(hb, wt2, o128);
  sage_eagg2<<<NT, 256, 0, stream>>>(tbase, gpart2, o128, invdeg, agg2);

  // global mean pool
  sage_gcnt<<<(NN + 255) / 256, 256, 0, stream>>>(batch, gcnt);
  sage_pool2<<<(NN + 127) / 128, 256, 0, stream>>>(o128, agg2, b2, batch, pool);
  sage_out<<<(NG * C2 + 255) / 256, 256, 0, stream>>>(pool, gcnt, out);
}

// Round 8
// 422.039 us; speedup vs baseline: 10.1436x; 10.1436x over previous
//
#include <hip/hip_runtime.h>

// GraphSAGE (2x SAGEConv mean + global_mean_pool) on MI355X.
// R7: revert to R5's pull-based CSR structure (R6's LDS-atomic edge-centric
// design was 23x slower: 66KB LDS -> 2 blocks/CU, ds_add latency chains,
// no real shard phase-alignment). New in R7: fp8-e4m3 gather operands.
// agg1 gathers xq (fp8 [NN][128], 2 lines/edge vs 4); agg2 gathers tq
// (fp8 [NN][64], 1 line/edge). HW cvt_pk fp8<->f32 (self-consistent
// quantizer), fp32 accumulation, 32-neighbor mean + 97-node pool average
// the quantization noise below threshold.

constexpr int NN = 100000;    // nodes
constexpr int NE = 3200000;   // edges
constexpr int C1 = 128;       // IN_C == HID_C
constexpr int C2 = 64;        // OUT_C
constexpr int NG = 1024;      // graphs

constexpr int NBK = (NN + 511) >> 9;   // 196 buckets of 512 nodes

typedef unsigned int u32;
typedef unsigned short u16;
typedef unsigned char u8;
typedef _Float16 f16;
typedef f16 f16x8 __attribute__((ext_vector_type(8)));
typedef float f32x4 __attribute__((ext_vector_type(4)));

__device__ __forceinline__ float h2f(u32 bits16) {
  f16 h; u16 b = (u16)bits16;
  __builtin_memcpy(&h, &b, 2);
  return (float)h;
}
__device__ __forceinline__ u16 f2h(float f) {
  f16 h = (f16)f; u16 b;
  __builtin_memcpy(&b, &h, 2);
  return b;
}
__device__ __forceinline__ u32 packh2(float a, float b) {
  return (u32)f2h(a) | ((u32)f2h(b) << 16);
}
// pack 4 floats -> 4 fp8 e4m3 (one u32)
__device__ __forceinline__ u32 packq4(float a, float b, float c, float d) {
  int q = 0;
  q = __builtin_amdgcn_cvt_pk_fp8_f32(a, b, q, false);
  q = __builtin_amdgcn_cvt_pk_fp8_f32(c, d, q, true);
  return (u32)q;
}

// ---------------- x -> fp16 + fp8 ----------------
__global__ __launch_bounds__(256)
void sage_x2h(const float* __restrict__ x, u16* __restrict__ xh,
              u32* __restrict__ xq) {
  const int i = blockIdx.x * 256 + threadIdx.x;       // one float4 per thread
  if (i >= NN * C1 / 4) return;
  const float4 v = ((const float4*)x)[i];
  uint2 o;
  o.x = packh2(v.x, v.y);
  o.y = packh2(v.z, v.w);
  ((uint2*)xh)[i] = o;
  xq[i] = packq4(v.x, v.y, v.z, v.w);
}

// ------------- weights -> fp16, transposed [N][K] -------------
__global__ __launch_bounds__(256)
void sage_wprep(const float* __restrict__ W1l, const float* __restrict__ W1r,
                const float* __restrict__ W2l, const float* __restrict__ W2r,
                u16* __restrict__ wt1, u16* __restrict__ wt2) {
  const int id = blockIdx.x * 256 + threadIdx.x;
  if (id < 128 * 256) {
    const int n = id >> 8, k = id & 255;
    const float v = (k < 128) ? W1l[k * 128 + n] : W1r[(k - 128) * 128 + n];
    wt1[id] = f2h(v);
  } else if (id < 128 * 256 + 128 * 128) {
    const int id2 = id - 128 * 256;
    const int n = id2 >> 7, k = id2 & 127;
    const float v = (n < 64) ? W2l[k * 64 + n] : W2r[k * 64 + (n - 64)];
    wt2[id2] = f2h(v);
  }
}

// ---------------- CSR build (R5): partition by 512-node dst bucket --------
__global__ __launch_bounds__(256)
void sage_phist(const int* __restrict__ edst, int* __restrict__ ghist) {
  __shared__ int h[NBK];
  for (int i = threadIdx.x; i < NBK; i += 256) h[i] = 0;
  __syncthreads();
  const int e0 = blockIdx.x * 4096 + threadIdx.x;
#pragma unroll
  for (int j = 0; j < 16; ++j) {
    const int e = e0 + j * 256;
    if (e < NE) atomicAdd(&h[edst[e] >> 9], 1);
  }
  __syncthreads();
  for (int i = threadIdx.x; i < NBK; i += 256)
    if (h[i]) atomicAdd(&ghist[i], h[i]);
}

__global__ __launch_bounds__(256)
void sage_pscan(const int* __restrict__ ghist, int* __restrict__ bbase,
                int* __restrict__ gcur) {
  __shared__ int s[256];
  const int t = threadIdx.x;
  const int v = (t < NBK) ? ghist[t] : 0;
  s[t] = v;
  __syncthreads();
  for (int d = 1; d < 256; d <<= 1) {
    const int a = (t >= d) ? s[t - d] : 0;
    __syncthreads();
    s[t] += a;
    __syncthreads();
  }
  if (t < NBK) { bbase[t] = s[t] - v; gcur[t] = s[t] - v; }
  if (t == 0) bbase[NBK] = NE;
}

// partition edges into bucket-contiguous runs of packed (src<<9)|(dst&511).
__global__ __launch_bounds__(256)
void sage_part(const int* __restrict__ esrc, const int* __restrict__ edst,
               int* __restrict__ gcur, u32* __restrict__ gpart) {
  __shared__ int h[NBK], cur[NBK];
  for (int i = threadIdx.x; i < NBK; i += 256) h[i] = 0;
  __syncthreads();
  const int e0 = blockIdx.x * 4096 + threadIdx.x;
#pragma unroll
  for (int j = 0; j < 16; ++j) {
    const int e = e0 + j * 256;
    if (e < NE) atomicAdd(&h[edst[e] >> 9], 1);
  }
  __syncthreads();
  for (int i = threadIdx.x; i < NBK; i += 256)
    cur[i] = h[i] ? atomicAdd(&gcur[i], h[i]) : 0;
  __syncthreads();
#pragma unroll
  for (int j = 0; j < 16; ++j) {
    const int e = e0 + j * 256;
    if (e < NE) {
      const int d = edst[e];
      const int p = atomicAdd(&cur[d >> 9], 1);
      gpart[p] = ((u32)esrc[e] << 9) | (u32)(d & 511);
    }
  }
}

// one block per bucket: LDS degree hist -> scan -> offs -> csr scatter into
// the bucket's ~64KB window (single block, short dirty-line lifetime).
__global__ __launch_bounds__(512)
void sage_bbuild(const int* __restrict__ bbase, const u32* __restrict__ gpart,
                 int* __restrict__ offs, int* __restrict__ csr) {
  __shared__ int ldeg[512], lcur[512], ssc[512];
  const int b = blockIdx.x, t = threadIdx.x;
  const int e0 = bbase[b], cnt = bbase[b + 1] - e0;
  ldeg[t] = 0;
  __syncthreads();
  for (int e = t; e < cnt; e += 512)
    atomicAdd(&ldeg[gpart[e0 + e] & 511], 1);
  __syncthreads();
  const int v = ldeg[t];
  ssc[t] = v;
  __syncthreads();
  for (int d = 1; d < 512; d <<= 1) {
    const int a = (t >= d) ? ssc[t - d] : 0;
    __syncthreads();
    ssc[t] += a;
    __syncthreads();
  }
  const int pre = ssc[t] - v;
  lcur[t] = pre;
  const int node = b * 512 + t;
  if (node < NN) offs[node] = e0 + pre;
  if (b == 0 && t == 0) offs[NN] = NE;
  __syncthreads();
  for (int e = t; e < cnt; e += 512) {
    const u32 pk = gpart[e0 + e];
    const int p = atomicAdd(&lcur[pk & 511], 1);
    csr[e0 + p] = (int)(pk >> 9);
  }
}

// ------------- aggregation 1: mean of xq (fp8) over in-neighbors -------
// wave per node; half-wave (32 lanes) covers one 128B fp8 row, lane owns
// channels 4l..4l+3; halves process even/odd edges, shfl_xor(32) combine.
__global__ __launch_bounds__(256)
void sage_agg1q(const int* __restrict__ offs, const int* __restrict__ csr,
                const u32* __restrict__ xq, u16* __restrict__ aggh) {
  const int node = blockIdx.x * 4 + (threadIdx.x >> 6);
  const int lane = threadIdx.x & 63;
  if (node >= NN) return;
  const int beg = offs[node], end = offs[node + 1];
  const int hf = lane >> 5, l = lane & 31;
  const u32* xb = xq + l;                             // row stride 32 u32
  float a0 = 0.f, a1 = 0.f, a2 = 0.f, a3 = 0.f;
  int e = beg + hf;
  for (; e + 6 < end; e += 8) {                       // 4 edges/half in flight
    const u32 g0 = xb[(size_t)csr[e] * 32];
    const u32 g1 = xb[(size_t)csr[e + 2] * 32];
    const u32 g2 = xb[(size_t)csr[e + 4] * 32];
    const u32 g3 = xb[(size_t)csr[e + 6] * 32];
    {
      const auto p = __builtin_amdgcn_cvt_pk_f32_fp8((int)g0, false);
      const auto q = __builtin_amdgcn_cvt_pk_f32_fp8((int)g0, true);
      a0 += p[0]; a1 += p[1]; a2 += q[0]; a3 += q[1];
    }
    {
      const auto p = __builtin_amdgcn_cvt_pk_f32_fp8((int)g1, false);
      const auto q = __builtin_amdgcn_cvt_pk_f32_fp8((int)g1, true);
      a0 += p[0]; a1 += p[1]; a2 += q[0]; a3 += q[1];
    }
    {
      const auto p = __builtin_amdgcn_cvt_pk_f32_fp8((int)g2, false);
      const auto q = __builtin_amdgcn_cvt_pk_f32_fp8((int)g2, true);
      a0 += p[0]; a1 += p[1]; a2 += q[0]; a3 += q[1];
    }
    {
      const auto p = __builtin_amdgcn_cvt_pk_f32_fp8((int)g3, false);
      const auto q = __builtin_amdgcn_cvt_pk_f32_fp8((int)g3, true);
      a0 += p[0]; a1 += p[1]; a2 += q[0]; a3 += q[1];
    }
  }
  for (; e < end; e += 2) {
    const u32 g = xb[(size_t)csr[e] * 32];
    const auto p = __builtin_amdgcn_cvt_pk_f32_fp8((int)g, false);
    const auto q = __builtin_amdgcn_cvt_pk_f32_fp8((int)g, true);
    a0 += p[0]; a1 += p[1]; a2 += q[0]; a3 += q[1];
  }
  a0 += __shfl_xor(a0, 32);
  a1 += __shfl_xor(a1, 32);
  a2 += __shfl_xor(a2, 32);
  a3 += __shfl_xor(a3, 32);
  if (hf == 0) {
    const float inv = 1.0f / fmaxf((float)(end - beg), 1.0f);
    uint2 o;
    o.x = packh2(a0 * inv, a1 * inv);
    o.y = packh2(a2 * inv, a3 * inv);
    *(uint2*)(aggh + (size_t)node * 128 + l * 4) = o;
  }
}

// ------------- convert t (o128 cols 0..63 fp16) -> tq fp8 [NN][64] -------
__global__ __launch_bounds__(256)
void sage_t2q(const u16* __restrict__ o128, u32* __restrict__ tq) {
  const int i = blockIdx.x * 256 + threadIdx.x;
  if (i >= NN * 16) return;
  const int n = i >> 4, c = i & 15;
  const uint2 v = *(const uint2*)(o128 + (size_t)n * 128 + c * 4);
  tq[(size_t)n * 16 + c] =
      packq4(h2f(v.x & 0xffffu), h2f(v.x >> 16),
             h2f(v.y & 0xffffu), h2f(v.y >> 16));
}

// ------------- aggregation 2: mean of tq (fp8) over in-neighbors -------
// wave per node; quarter-wave (16 lanes) covers one 64B fp8 row (1 line),
// lane owns channels 4*l4..4*l4+3; 4 groups process edge strides,
// shfl_xor(16)+(32) combine.
__global__ __launch_bounds__(256)
void sage_agg2q(const int* __restrict__ offs, const int* __restrict__ csr,
                const u32* __restrict__ tq, float* __restrict__ agg) {
  const int node = blockIdx.x * 4 + (threadIdx.x >> 6);
  const int lane = threadIdx.x & 63;
  if (node >= NN) return;
  const int beg = offs[node], end = offs[node + 1];
  const int grp = lane >> 4, l4 = lane & 15;
  const u32* tb = tq + l4;                            // row stride 16 u32
  float a0 = 0.f, a1 = 0.f, a2 = 0.f, a3 = 0.f;
  int e = beg + grp;
  for (; e + 4 < end; e += 8) {                       // 2 edges/group in flight
    const u32 g0 = tb[(size_t)csr[e] * 16];
    const u32 g1 = tb[(size_t)csr[e + 4] * 16];
    {
      const auto p = __builtin_amdgcn_cvt_pk_f32_fp8((int)g0, false);
      const auto q = __builtin_amdgcn_cvt_pk_f32_fp8((int)g0, true);
      a0 += p[0]; a1 += p[1]; a2 += q[0]; a3 += q[1];
    }
    {
      const auto p = __builtin_amdgcn_cvt_pk_f32_fp8((int)g1, false);
      const auto q = __builtin_amdgcn_cvt_pk_f32_fp8((int)g1, true);
      a0 += p[0]; a1 += p[1]; a2 += q[0]; a3 += q[1];
    }
  }
  for (; e < end; e += 4) {
    const u32 g = tb[(size_t)csr[e] * 16];
    const auto p = __builtin_amdgcn_cvt_pk_f32_fp8((int)g, false);
    const auto q = __builtin_amdgcn_cvt_pk_f32_fp8((int)g, true);
    a0 += p[0]; a1 += p[1]; a2 += q[0]; a3 += q[1];
  }
  a0 += __shfl_xor(a0, 16); a0 += __shfl_xor(a0, 32);
  a1 += __shfl_xor(a1, 16); a1 += __shfl_xor(a1, 32);
  a2 += __shfl_xor(a2, 16); a2 += __shfl_xor(a2, 32);
  a3 += __shfl_xor(a3, 16); a3 += __shfl_xor(a3, 32);
  if (grp == 0) {
    const float inv = 1.0f / fmaxf((float)(end - beg), 1.0f);
    *(float4*)(agg + (size_t)node * 64 + l4 * 4) =
        make_float4(a0 * inv, a1 * inv, a2 * inv, a3 * inv);
  }
}

// ------------- MFMA GEMM 1: H = relu(A1@W1l + A2@W1r + b1), fp16 out -------
__global__ __launch_bounds__(256)
void sage_mgemm1(const u16* __restrict__ A1, const u16* __restrict__ A2,
                 const u16* __restrict__ wt1, const float* __restrict__ bias,
                 u16* __restrict__ H) {
  __shared__ __align__(16) u16 As[2][64][128];
  const int t = threadIdx.x;
  const int r0 = blockIdx.x * 64;
#pragma unroll
  for (int i = 0; i < 8; ++i) {                       // 2048 16B-chunk loads
    const int id = i * 256 + t;
    const int buf = id >> 10;
    const int id2 = id & 1023;
    const int row = id2 >> 4, c = id2 & 15;
    int gr = r0 + row; gr = (gr < NN) ? gr : NN - 1;  // clamp; store guarded
    const uint4 v = *(const uint4*)((buf ? A2 : A1) + (size_t)gr * 128 + c * 8);
    *(uint4*)(&As[buf][row][(c ^ (row & 7)) * 8]) = v;
  }
  __syncthreads();
  const int w = t >> 6, l = t & 63;
  const int lr = l & 15, lk = l >> 4;
  const int rowl = w * 16 + lr;
  f32x4 acc[8];
#pragma unroll
  for (int c = 0; c < 8; ++c) acc[c] = (f32x4){0.f, 0.f, 0.f, 0.f};
#pragma unroll
  for (int kt = 0; kt < 8; ++kt) {                    // K = 256 in 32-steps
    const int buf = kt >> 2, kk = kt & 3;
    const int ch = (kk * 4 + lk) ^ (rowl & 7);
    const f16x8 a = *(const f16x8*)(&As[buf][rowl][ch * 8]);
#pragma unroll
    for (int c = 0; c < 8; ++c) {
      const f16x8 b = *(const f16x8*)(wt1 + ((c * 16 + lr) * 256 + kt * 32 + lk * 8));
      acc[c] = __builtin_amdgcn_mfma_f32_16x16x32_f16(a, b, acc[c], 0, 0, 0);
    }
  }
#pragma unroll
  for (int c = 0; c < 8; ++c) {                       // C/D: col=l&15, row=lk*4+j
    const int col = c * 16 + lr;
    const float bv = bias[col];
#pragma unroll
    for (int j = 0; j < 4; ++j) {
      const int row = r0 + w * 16 + lk * 4 + j;
      if (row < NN) H[(size_t)row * 128 + col] = f2h(fmaxf(acc[c][j] + bv, 0.f));
    }
  }
}

// ------------- MFMA GEMM 2: O = H @ [W2l | W2r], fp16 out [NN][128] -------
__global__ __launch_bounds__(256)
void sage_mgemm2(const u16* __restrict__ A, const u16* __restrict__ wt2,
                 u16* __restrict__ O) {
  __shared__ __align__(16) u16 As[64][128];
  const int t = threadIdx.x;
  const int r0 = blockIdx.x * 64;
#pragma unroll
  for (int i = 0; i < 4; ++i) {
    const int id = i * 256 + t;
    const int row = id >> 4, c = id & 15;
    int gr = r0 + row; gr = (gr < NN) ? gr : NN - 1;
    const uint4 v = *(const uint4*)(A + (size_t)gr * 128 + c * 8);
    *(uint4*)(&As[row][(c ^ (row & 7)) * 8]) = v;
  }
  __syncthreads();
  const int w = t >> 6, l = t & 63;
  const int lr = l & 15, lk = l >> 4;
  const int rowl = w * 16 + lr;
  f32x4 acc[8];
#pragma unroll
  for (int c = 0; c < 8; ++c) acc[c] = (f32x4){0.f, 0.f, 0.f, 0.f};
#pragma unroll
  for (int kt = 0; kt < 4; ++kt) {                    // K = 128
    const int ch = (kt * 4 + lk) ^ (rowl & 7);
    const f16x8 a = *(const f16x8*)(&As[rowl][ch * 8]);
#pragma unroll
    for (int c = 0; c < 8; ++c) {
      const f16x8 b = *(const f16x8*)(wt2 + ((c * 16 + lr) * 128 + kt * 32 + lk * 8));
      acc[c] = __builtin_amdgcn_mfma_f32_16x16x32_f16(a, b, acc[c], 0, 0, 0);
    }
  }
#pragma unroll
  for (int c = 0; c < 8; ++c) {
    const int col = c * 16 + lr;
#pragma unroll
    for (int j = 0; j < 4; ++j) {
      const int row = r0 + w * 16 + lk * 4 + j;
      if (row < NN) O[(size_t)row * 128 + col] = f2h(acc[c][j]);
    }
  }
}

// ------------- pooling -------------
__global__ __launch_bounds__(256)
void sage_gcnt(const int* __restrict__ batch, int* __restrict__ gcnt) {
  const int n = blockIdx.x * 256 + threadIdx.x;
  if (n < NN) atomicAdd(&gcnt[batch[n]], 1);
}

// batch sorted: accumulate runs locally, one atomic per graph change.
__global__ __launch_bounds__(256)
void sage_pool2(const u16* __restrict__ o128, const float* __restrict__ agg2,
                const float* __restrict__ b2, const int* __restrict__ batch,
                float* __restrict__ pool) {
  const int t = threadIdx.x;
  const int c = t & 63, sl = t >> 6;
  const int n0 = blockIdx.x * 128;
  const float bv = b2[c];
  float acc = 0.f;
  int curg = -1;
  for (int n = n0 + sl; n < n0 + 128 && n < NN; n += 4) {
    const int g = batch[n];
    const float v = h2f(o128[(size_t)n * 128 + 64 + c]) + agg2[n * C2 + c] + bv;
    if (g != curg) {
      if (curg >= 0) atomicAdd(&pool[curg * C2 + c], acc);
      curg = g;
      acc = v;
    } else {
      acc += v;
    }
  }
  if (curg >= 0) atomicAdd(&pool[curg * C2 + c], acc);
}

__global__ __launch_bounds__(256)
void sage_out(const float* __restrict__ pool, const int* __restrict__ gcnt,
              float* __restrict__ out) {
  const int i = blockIdx.x * 256 + threadIdx.x;
  if (i >= NG * C2) return;
  out[i] = pool[i] / fmaxf((float)gcnt[i >> 6], 1.0f);
}

extern "C" void kernel_launch(void* const* d_in, const int* in_sizes, int n_in,
                              void* d_out, int out_size, void* d_ws, size_t ws_size,
                              hipStream_t stream) {
  (void)in_sizes; (void)n_in; (void)out_size; (void)ws_size;
  const float* x     = (const float*)d_in[0];
  const float* W1l   = (const float*)d_in[1];
  const float* b1    = (const float*)d_in[2];
  const float* W1r   = (const float*)d_in[3];
  const float* W2l   = (const float*)d_in[4];
  const float* b2    = (const float*)d_in[5];
  const float* W2r   = (const float*)d_in[6];
  const int*   ei    = (const int*)d_in[7];   // [2, NE]: row0 = src, row1 = dst
  const int*   batch = (const int*)d_in[8];
  const int* esrc = ei;
  const int* edst = ei + NE;
  float* out = (float*)d_out;

  // ---- workspace carve-out (~91 MB) ----
  char* base = (char*)d_ws;
  size_t off = 0;
  auto take = [&](size_t bytes) -> char* {
    char* p = base + off;
    off += (bytes + 255) & ~(size_t)255;
    return p;
  };
  int* ghist    = (int*)take((size_t)NBK * 4);
  int* bbase    = (int*)take((size_t)(NBK + 1) * 4);
  int* gcur     = (int*)take((size_t)NBK * 4);
  int* offs     = (int*)take((size_t)(NN + 1) * 4);
  int* csr      = (int*)take((size_t)NE * 4);
  char* bufA    = take((size_t)NN * 256);   // xh (f16 NNx128) -> o128 (f16 NNx128)
  char* bufB    = take((size_t)NN * 256);   // agg1h (f16 NNx128) -> agg2 (f32 NNx64)
  char* bufC    = take((size_t)NN * 256);   // [gpart(12.8M) | xq(12.8M)] -> hb -> tq
  float* pool   = (float*)take((size_t)NG * C2 * 4);
  int*  gcnt    = (int*)take((size_t)NG * 4);
  u16*  wt1     = (u16*)take((size_t)128 * 256 * 2);
  u16*  wt2     = (u16*)take((size_t)128 * 128 * 2);

  u16*   xh    = (u16*)bufA;
  u16*   o128  = (u16*)bufA;                // gemm2 out (xh dead by then)
  u16*   agg1h = (u16*)bufB;
  float* agg2  = (float*)bufB;              // agg1h dead after mgemm1
  u32*   gpart = (u32*)bufC;                // dead after bbuild
  u32*   xq    = (u32*)(bufC + (size_t)NE * 4);   // fp8 x; dead after agg1q
  u16*   hb    = (u16*)bufC;                // written by mgemm1 (gpart+xq dead)
  u32*   tq    = (u32*)bufC;                // fp8 t; written after mgemm2 (hb dead)

  hipMemsetAsync(ghist, 0, (size_t)NBK * 4, stream);
  hipMemsetAsync(pool, 0, (size_t)NG * C2 * 4, stream);
  hipMemsetAsync(gcnt, 0, (size_t)NG * 4, stream);

  sage_wprep<<<192, 256, 0, stream>>>(W1l, W1r, W2l, W2r, wt1, wt2);
  sage_x2h<<<(NN * C1 / 4 + 255) / 256, 256, 0, stream>>>(x, xh, xq);

  // CSR build (R5)
  const int PB = (NE + 4095) / 4096;        // 782 partition blocks
  sage_phist<<<PB, 256, 0, stream>>>(edst, ghist);
  sage_pscan<<<1, 256, 0, stream>>>(ghist, bbase, gcur);
  sage_part<<<PB, 256, 0, stream>>>(esrc, edst, gcur, gpart);
  sage_bbuild<<<NBK, 512, 0, stream>>>(bbase, gpart, offs, csr);

  // layer 1
  sage_agg1q<<<(NN + 3) / 4, 256, 0, stream>>>(offs, csr, xq, agg1h);
  sage_mgemm1<<<(NN + 63) / 64, 256, 0, stream>>>(agg1h, xh, wt1, b1, hb);

  // layer 2 (transform-then-aggregate: mean(h)@W2l == mean(h@W2l));
  // o128 = h @ [W2l | W2r]  (cols 0..63 = t, 64..127 = t2)
  sage_mgemm2<<<(NN + 63) / 64, 256, 0, stream>>>(hb, wt2, o128);
  sage_t2q<<<(NN * 16 + 255) / 256, 256, 0, stream>>>(o128, tq);
  sage_agg2q<<<(NN + 3) / 4, 256, 0, stream>>>(offs, csr, tq, agg2);

  // global mean pool
  sage_gcnt<<<(NN + 255) / 256, 256, 0, stream>>>(batch, gcnt);
  sage_pool2<<<(NN + 127) / 128, 256, 0, stream>>>(o128, agg2, b2, batch, pool);
  sage_out<<<(NG * C2 + 255) / 256, 256, 0, stream>>>(pool, gcnt, out);
}

// Round 9
// 364.635 us; speedup vs baseline: 11.7405x; 1.1574x over previous
//
#include <hip/hip_runtime.h>

// GraphSAGE (2x SAGEConv mean + global_mean_pool) on MI355X.
// R8: agg kernels rebuilt for memory-level parallelism (R7 profile: agg1q
// VALU floor ~15us but dur 76us at VALUBusy 55% -> L2-miss latency bound):
// quarter-wave uint2 gathers, aligned int4 csr windows, 2-window unroll =
// 8 gathers in flight/lane. Pipeline fusion: wprep+x2h, t2q->mgemm2 epilogue
// (skip dead lo-half of o128), gcnt->pool2, 1 memset, int4 edge reads in
// phist/part. 20 -> 12 dispatches. agg2 output fp16.

constexpr int NN = 100000;    // nodes
constexpr int NE = 3200000;   // edges
constexpr int C1 = 128;       // IN_C == HID_C
constexpr int C2 = 64;        // OUT_C
constexpr int NG = 1024;      // graphs

constexpr int NBK = (NN + 511) >> 9;   // 196 buckets of 512 nodes

typedef unsigned int u32;
typedef unsigned short u16;
typedef unsigned char u8;
typedef _Float16 f16;
typedef f16 f16x8 __attribute__((ext_vector_type(8)));
typedef float f32x4 __attribute__((ext_vector_type(4)));

__device__ __forceinline__ float h2f(u32 bits16) {
  f16 h; u16 b = (u16)bits16;
  __builtin_memcpy(&h, &b, 2);
  return (float)h;
}
__device__ __forceinline__ u16 f2h(float f) {
  f16 h = (f16)f; u16 b;
  __builtin_memcpy(&b, &h, 2);
  return b;
}
__device__ __forceinline__ u32 packh2(float a, float b) {
  return (u32)f2h(a) | ((u32)f2h(b) << 16);
}
// pack 4 floats -> 4 fp8 e4m3 (one u32)
__device__ __forceinline__ u32 packq4(float a, float b, float c, float d) {
  int q = 0;
  q = __builtin_amdgcn_cvt_pk_fp8_f32(a, b, q, false);
  q = __builtin_amdgcn_cvt_pk_fp8_f32(c, d, q, true);
  return (u32)q;
}

// ---------------- fused: x -> fp16 + fp8, weights -> fp16 [N][K] ----------
// ids [0, NN*32): x float4 -> xh fp16x4 + xq fp8x4
// ids [NN*32, +32768): wt1 [128 n][256 k]; ids [.., +16384): wt2 [128 n][128 k]
__global__ __launch_bounds__(256)
void sage_x2hw(const float* __restrict__ x, u16* __restrict__ xh,
               u32* __restrict__ xq,
               const float* __restrict__ W1l, const float* __restrict__ W1r,
               const float* __restrict__ W2l, const float* __restrict__ W2r,
               u16* __restrict__ wt1, u16* __restrict__ wt2) {
  const int id = blockIdx.x * 256 + threadIdx.x;
  constexpr int NX = NN * 32;
  if (id < NX) {
    const float4 v = ((const float4*)x)[id];
    uint2 o;
    o.x = packh2(v.x, v.y);
    o.y = packh2(v.z, v.w);
    ((uint2*)xh)[id] = o;
    xq[id] = packq4(v.x, v.y, v.z, v.w);
  } else if (id < NX + 128 * 256) {
    const int id2 = id - NX;
    const int n = id2 >> 8, k = id2 & 255;
    const float v = (k < 128) ? W1l[k * 128 + n] : W1r[(k - 128) * 128 + n];
    wt1[id2] = f2h(v);
  } else if (id < NX + 128 * 256 + 128 * 128) {
    const int id3 = id - NX - 128 * 256;
    const int n = id3 >> 7, k = id3 & 127;
    const float v = (n < 64) ? W2l[k * 64 + n] : W2r[k * 64 + (n - 64)];
    wt2[id3] = f2h(v);
  }
}

// ---------------- CSR build: partition by 512-node dst bucket -------------
__global__ __launch_bounds__(256)
void sage_phist(const int* __restrict__ edst, int* __restrict__ ghist) {
  __shared__ int h[NBK];
  for (int i = threadIdx.x; i < NBK; i += 256) h[i] = 0;
  __syncthreads();
  const int e0 = blockIdx.x * 4096 + threadIdx.x * 4;
#pragma unroll
  for (int j = 0; j < 4; ++j) {
    const int e = e0 + j * 1024;
    if (e < NE) {
      const int4 d = *(const int4*)(edst + e);
      atomicAdd(&h[d.x >> 9], 1);
      atomicAdd(&h[d.y >> 9], 1);
      atomicAdd(&h[d.z >> 9], 1);
      atomicAdd(&h[d.w >> 9], 1);
    }
  }
  __syncthreads();
  for (int i = threadIdx.x; i < NBK; i += 256)
    if (h[i]) atomicAdd(&ghist[i], h[i]);
}

__global__ __launch_bounds__(256)
void sage_pscan(const int* __restrict__ ghist, int* __restrict__ bbase,
                int* __restrict__ gcur) {
  __shared__ int s[256];
  const int t = threadIdx.x;
  const int v = (t < NBK) ? ghist[t] : 0;
  s[t] = v;
  __syncthreads();
  for (int d = 1; d < 256; d <<= 1) {
    const int a = (t >= d) ? s[t - d] : 0;
    __syncthreads();
    s[t] += a;
    __syncthreads();
  }
  if (t < NBK) { bbase[t] = s[t] - v; gcur[t] = s[t] - v; }
  if (t == 0) bbase[NBK] = NE;
}

// partition edges into bucket-contiguous runs of packed (src<<9)|(dst&511).
__global__ __launch_bounds__(256)
void sage_part(const int* __restrict__ esrc, const int* __restrict__ edst,
               int* __restrict__ gcur, u32* __restrict__ gpart) {
  __shared__ int h[NBK], cur[NBK];
  for (int i = threadIdx.x; i < NBK; i += 256) h[i] = 0;
  __syncthreads();
  const int e0 = blockIdx.x * 4096 + threadIdx.x * 4;
#pragma unroll
  for (int j = 0; j < 4; ++j) {
    const int e = e0 + j * 1024;
    if (e < NE) {
      const int4 d = *(const int4*)(edst + e);
      atomicAdd(&h[d.x >> 9], 1);
      atomicAdd(&h[d.y >> 9], 1);
      atomicAdd(&h[d.z >> 9], 1);
      atomicAdd(&h[d.w >> 9], 1);
    }
  }
  __syncthreads();
  for (int i = threadIdx.x; i < NBK; i += 256)
    cur[i] = h[i] ? atomicAdd(&gcur[i], h[i]) : 0;
  __syncthreads();
#pragma unroll
  for (int j = 0; j < 4; ++j) {
    const int e = e0 + j * 1024;
    if (e < NE) {
      const int4 d = *(const int4*)(edst + e);
      const int4 s = *(const int4*)(esrc + e);
      int p;
      p = atomicAdd(&cur[d.x >> 9], 1); gpart[p] = ((u32)s.x << 9) | (u32)(d.x & 511);
      p = atomicAdd(&cur[d.y >> 9], 1); gpart[p] = ((u32)s.y << 9) | (u32)(d.y & 511);
      p = atomicAdd(&cur[d.z >> 9], 1); gpart[p] = ((u32)s.z << 9) | (u32)(d.z & 511);
      p = atomicAdd(&cur[d.w >> 9], 1); gpart[p] = ((u32)s.w << 9) | (u32)(d.w & 511);
    }
  }
}

// one block per bucket: LDS degree hist -> scan -> offs -> csr scatter.
__global__ __launch_bounds__(512)
void sage_bbuild(const int* __restrict__ bbase, const u32* __restrict__ gpart,
                 int* __restrict__ offs, int* __restrict__ csr) {
  __shared__ int ldeg[512], lcur[512], ssc[512];
  const int b = blockIdx.x, t = threadIdx.x;
  const int e0 = bbase[b], cnt = bbase[b + 1] - e0;
  ldeg[t] = 0;
  __syncthreads();
  for (int e = t; e < cnt; e += 512)
    atomicAdd(&ldeg[gpart[e0 + e] & 511], 1);
  __syncthreads();
  const int v = ldeg[t];
  ssc[t] = v;
  __syncthreads();
  for (int d = 1; d < 512; d <<= 1) {
    const int a = (t >= d) ? ssc[t - d] : 0;
    __syncthreads();
    ssc[t] += a;
    __syncthreads();
  }
  const int pre = ssc[t] - v;
  lcur[t] = pre;
  const int node = b * 512 + t;
  if (node < NN) offs[node] = e0 + pre;
  if (b == 0 && t == 0) offs[NN] = NE;
  __syncthreads();
  for (int e = t; e < cnt; e += 512) {
    const u32 pk = gpart[e0 + e];
    const int p = atomicAdd(&lcur[pk & 511], 1);
    csr[e0 + p] = (int)(pk >> 9);
  }
}

// ------------- aggregation 1: mean of xq (fp8 [NN][128]) -------------
// wave per node; 4 groups of 16 lanes, lane owns ch l4*8..+7 (uint2 = 8 fp8).
// Aligned int4 csr windows, per-edge mask, 2 windows unrolled -> 8 gathers
// in flight per lane.
__global__ __launch_bounds__(256)
void sage_agg1q(const int* __restrict__ offs, const int* __restrict__ csr,
                const u32* __restrict__ xq, u16* __restrict__ aggh) {
  const int node = blockIdx.x * 4 + (threadIdx.x >> 6);
  const int lane = threadIdx.x & 63;
  if (node >= NN) return;
  const int beg = offs[node], end = offs[node + 1];
  const int grp = lane >> 4, l4 = lane & 15;
  const uint2* xb = (const uint2*)xq + l4;            // row stride 16 uint2
  float a0 = 0, a1 = 0, a2 = 0, a3 = 0, a4 = 0, a5 = 0, a6 = 0, a7 = 0;
  for (int w = (beg & ~3) + grp * 4; w < end; w += 32) {   // 2 windows/iter
    const int4 iA = *(const int4*)(csr + w);
    const int4 iB = *(const int4*)(csr + w + 16);     // may be masked out
    const int idx[8] = {iA.x, iA.y, iA.z, iA.w, iB.x, iB.y, iB.z, iB.w};
#pragma unroll
    for (int j = 0; j < 8; ++j) {
      const int e = w + ((j < 4) ? j : (12 + j));     // w+j or w+16+(j-4)
      if (e >= beg && e < end) {
        const uint2 g = xb[(size_t)idx[j] * 16];
        const auto p0 = __builtin_amdgcn_cvt_pk_f32_fp8((int)g.x, false);
        const auto p1 = __builtin_amdgcn_cvt_pk_f32_fp8((int)g.x, true);
        const auto p2 = __builtin_amdgcn_cvt_pk_f32_fp8((int)g.y, false);
        const auto p3 = __builtin_amdgcn_cvt_pk_f32_fp8((int)g.y, true);
        a0 += p0[0]; a1 += p0[1]; a2 += p1[0]; a3 += p1[1];
        a4 += p2[0]; a5 += p2[1]; a6 += p3[0]; a7 += p3[1];
      }
    }
  }
  a0 += __shfl_xor(a0, 16); a0 += __shfl_xor(a0, 32);
  a1 += __shfl_xor(a1, 16); a1 += __shfl_xor(a1, 32);
  a2 += __shfl_xor(a2, 16); a2 += __shfl_xor(a2, 32);
  a3 += __shfl_xor(a3, 16); a3 += __shfl_xor(a3, 32);
  a4 += __shfl_xor(a4, 16); a4 += __shfl_xor(a4, 32);
  a5 += __shfl_xor(a5, 16); a5 += __shfl_xor(a5, 32);
  a6 += __shfl_xor(a6, 16); a6 += __shfl_xor(a6, 32);
  a7 += __shfl_xor(a7, 16); a7 += __shfl_xor(a7, 32);
  if (lane < 16) {
    const float inv = 1.0f / fmaxf((float)(end - beg), 1.0f);
    uint4 o;
    o.x = packh2(a0 * inv, a1 * inv);
    o.y = packh2(a2 * inv, a3 * inv);
    o.z = packh2(a4 * inv, a5 * inv);
    o.w = packh2(a6 * inv, a7 * inv);
    *(uint4*)(aggh + (size_t)node * 128 + l4 * 8) = o;
  }
}

// ------------- aggregation 2: mean of tq (fp8 [NN][64]) -> fp16 -------------
// wave per node; 8 groups of 8 lanes, lane owns ch l8*8..+7 (uint2 = 8 fp8).
__global__ __launch_bounds__(256)
void sage_agg2q(const int* __restrict__ offs, const int* __restrict__ csr,
                const u32* __restrict__ tq, u16* __restrict__ agg2h) {
  const int node = blockIdx.x * 4 + (threadIdx.x >> 6);
  const int lane = threadIdx.x & 63;
  if (node >= NN) return;
  const int beg = offs[node], end = offs[node + 1];
  const int grp = lane >> 3, l8 = lane & 7;
  const uint2* tb = (const uint2*)tq + l8;            // row stride 8 uint2
  float a0 = 0, a1 = 0, a2 = 0, a3 = 0, a4 = 0, a5 = 0, a6 = 0, a7 = 0;
  for (int w = (beg & ~3) + grp * 4; w < end; w += 64) {   // 2 windows/iter
    const int4 iA = *(const int4*)(csr + w);
    const int4 iB = *(const int4*)(csr + w + 32);
    const int idx[8] = {iA.x, iA.y, iA.z, iA.w, iB.x, iB.y, iB.z, iB.w};
#pragma unroll
    for (int j = 0; j < 8; ++j) {
      const int e = w + ((j < 4) ? j : (28 + j));     // w+j or w+32+(j-4)
      if (e >= beg && e < end) {
        const uint2 g = tb[(size_t)idx[j] * 8];
        const auto p0 = __builtin_amdgcn_cvt_pk_f32_fp8((int)g.x, false);
        const auto p1 = __builtin_amdgcn_cvt_pk_f32_fp8((int)g.x, true);
        const auto p2 = __builtin_amdgcn_cvt_pk_f32_fp8((int)g.y, false);
        const auto p3 = __builtin_amdgcn_cvt_pk_f32_fp8((int)g.y, true);
        a0 += p0[0]; a1 += p0[1]; a2 += p1[0]; a3 += p1[1];
        a4 += p2[0]; a5 += p2[1]; a6 += p3[0]; a7 += p3[1];
      }
    }
  }
  a0 += __shfl_xor(a0, 8); a0 += __shfl_xor(a0, 16); a0 += __shfl_xor(a0, 32);
  a1 += __shfl_xor(a1, 8); a1 += __shfl_xor(a1, 16); a1 += __shfl_xor(a1, 32);
  a2 += __shfl_xor(a2, 8); a2 += __shfl_xor(a2, 16); a2 += __shfl_xor(a2, 32);
  a3 += __shfl_xor(a3, 8); a3 += __shfl_xor(a3, 16); a3 += __shfl_xor(a3, 32);
  a4 += __shfl_xor(a4, 8); a4 += __shfl_xor(a4, 16); a4 += __shfl_xor(a4, 32);
  a5 += __shfl_xor(a5, 8); a5 += __shfl_xor(a5, 16); a5 += __shfl_xor(a5, 32);
  a6 += __shfl_xor(a6, 8); a6 += __shfl_xor(a6, 16); a6 += __shfl_xor(a6, 32);
  a7 += __shfl_xor(a7, 8); a7 += __shfl_xor(a7, 16); a7 += __shfl_xor(a7, 32);
  if (lane < 8) {
    const float inv = 1.0f / fmaxf((float)(end - beg), 1.0f);
    uint4 o;
    o.x = packh2(a0 * inv, a1 * inv);
    o.y = packh2(a2 * inv, a3 * inv);
    o.z = packh2(a4 * inv, a5 * inv);
    o.w = packh2(a6 * inv, a7 * inv);
    *(uint4*)(agg2h + (size_t)node * 64 + l8 * 8) = o;
  }
}

// ------------- MFMA GEMM 1: H = relu(A1@W1l + A2@W1r + b1), fp16 out -------
__global__ __launch_bounds__(256)
void sage_mgemm1(const u16* __restrict__ A1, const u16* __restrict__ A2,
                 const u16* __restrict__ wt1, const float* __restrict__ bias,
                 u16* __restrict__ H) {
  __shared__ __align__(16) u16 As[2][64][128];
  const int t = threadIdx.x;
  const int r0 = blockIdx.x * 64;
#pragma unroll
  for (int i = 0; i < 8; ++i) {                       // 2048 16B-chunk loads
    const int id = i * 256 + t;
    const int buf = id >> 10;
    const int id2 = id & 1023;
    const int row = id2 >> 4, c = id2 & 15;
    int gr = r0 + row; gr = (gr < NN) ? gr : NN - 1;  // clamp; store guarded
    const uint4 v = *(const uint4*)((buf ? A2 : A1) + (size_t)gr * 128 + c * 8);
    *(uint4*)(&As[buf][row][(c ^ (row & 7)) * 8]) = v;
  }
  __syncthreads();
  const int w = t >> 6, l = t & 63;
  const int lr = l & 15, lk = l >> 4;
  const int rowl = w * 16 + lr;
  f32x4 acc[8];
#pragma unroll
  for (int c = 0; c < 8; ++c) acc[c] = (f32x4){0.f, 0.f, 0.f, 0.f};
#pragma unroll
  for (int kt = 0; kt < 8; ++kt) {                    // K = 256 in 32-steps
    const int buf = kt >> 2, kk = kt & 3;
    const int ch = (kk * 4 + lk) ^ (rowl & 7);
    const f16x8 a = *(const f16x8*)(&As[buf][rowl][ch * 8]);
#pragma unroll
    for (int c = 0; c < 8; ++c) {
      const f16x8 b = *(const f16x8*)(wt1 + ((c * 16 + lr) * 256 + kt * 32 + lk * 8));
      acc[c] = __builtin_amdgcn_mfma_f32_16x16x32_f16(a, b, acc[c], 0, 0, 0);
    }
  }
#pragma unroll
  for (int c = 0; c < 8; ++c) {                       // C/D: col=l&15, row=lk*4+j
    const int col = c * 16 + lr;
    const float bv = bias[col];
#pragma unroll
    for (int j = 0; j < 4; ++j) {
      const int row = r0 + w * 16 + lk * 4 + j;
      if (row < NN) H[(size_t)row * 128 + col] = f2h(fmaxf(acc[c][j] + bv, 0.f));
    }
  }
}

// ------------- MFMA GEMM 2: cols 0..63 (t) -> tq fp8; cols 64..127 (t2) ----
// -> o128 hi-half fp16. wt2 [128 n][128 k] fp16; no bias (b2 added in pool).
__global__ __launch_bounds__(256)
void sage_mgemm2(const u16* __restrict__ A, const u16* __restrict__ wt2,
                 u16* __restrict__ O, u8* __restrict__ tqb) {
  __shared__ __align__(16) u16 As[64][128];
  const int t = threadIdx.x;
  const int r0 = blockIdx.x * 64;
#pragma unroll
  for (int i = 0; i < 4; ++i) {
    const int id = i * 256 + t;
    const int row = id >> 4, c = id & 15;
    int gr = r0 + row; gr = (gr < NN) ? gr : NN - 1;
    const uint4 v = *(const uint4*)(A + (size_t)gr * 128 + c * 8);
    *(uint4*)(&As[row][(c ^ (row & 7)) * 8]) = v;
  }
  __syncthreads();
  const int w = t >> 6, l = t & 63;
  const int lr = l & 15, lk = l >> 4;
  const int rowl = w * 16 + lr;
  f32x4 acc[8];
#pragma unroll
  for (int c = 0; c < 8; ++c) acc[c] = (f32x4){0.f, 0.f, 0.f, 0.f};
#pragma unroll
  for (int kt = 0; kt < 4; ++kt) {                    // K = 128
    const int ch = (kt * 4 + lk) ^ (rowl & 7);
    const f16x8 a = *(const f16x8*)(&As[rowl][ch * 8]);
#pragma unroll
    for (int c = 0; c < 8; ++c) {
      const f16x8 b = *(const f16x8*)(wt2 + ((c * 16 + lr) * 128 + kt * 32 + lk * 8));
      acc[c] = __builtin_amdgcn_mfma_f32_16x16x32_f16(a, b, acc[c], 0, 0, 0);
    }
  }
#pragma unroll
  for (int c = 0; c < 8; ++c) {
    const int col = c * 16 + lr;
#pragma unroll
    for (int j = 0; j < 4; ++j) {
      const int row = r0 + w * 16 + lk * 4 + j;
      if (row < NN) {
        if (col < 64) {                               // t -> fp8 byte
          const int pk = __builtin_amdgcn_cvt_pk_fp8_f32(acc[c][j], acc[c][j], 0, false);
          tqb[(size_t)row * 64 + col] = (u8)pk;
        } else {                                      // t2 -> o128 hi fp16
          O[(size_t)row * 128 + col] = f2h(acc[c][j]);
        }
      }
    }
  }
}

// ------------- pooling (fused node counting, sorted-batch runs) -------------
__global__ __launch_bounds__(256)
void sage_pool2(const u16* __restrict__ o128, const u16* __restrict__ agg2h,
                const float* __restrict__ b2, const int* __restrict__ batch,
                float* __restrict__ pool, int* __restrict__ gcnt) {
  const int t = threadIdx.x;
  const int c = t & 63, sl = t >> 6;
  const int n0 = blockIdx.x * 128;
  const float bv = b2[c];
  float acc = 0.f;
  int curg = -1, cnt = 0;
  for (int n = n0 + sl; n < n0 + 128 && n < NN; n += 4) {
    const int g = batch[n];
    const float v = h2f(o128[(size_t)n * 128 + 64 + c]) +
                    h2f(agg2h[(size_t)n * 64 + c]) + bv;
    if (g != curg) {
      if (curg >= 0) {
        atomicAdd(&pool[curg * C2 + c], acc);
        if (c == 0) atomicAdd(&gcnt[curg], cnt);
      }
      curg = g; acc = v; cnt = 1;
    } else {
      acc += v; cnt += 1;
    }
  }
  if (curg >= 0) {
    atomicAdd(&pool[curg * C2 + c], acc);
    if (c == 0) atomicAdd(&gcnt[curg], cnt);
  }
}

__global__ __launch_bounds__(256)
void sage_out(const float* __restrict__ pool, const int* __restrict__ gcnt,
              float* __restrict__ out) {
  const int i = blockIdx.x * 256 + threadIdx.x;
  if (i >= NG * C2) return;
  out[i] = pool[i] / fmaxf((float)gcnt[i >> 6], 1.0f);
}

extern "C" void kernel_launch(void* const* d_in, const int* in_sizes, int n_in,
                              void* d_out, int out_size, void* d_ws, size_t ws_size,
                              hipStream_t stream) {
  (void)in_sizes; (void)n_in; (void)out_size; (void)ws_size;
  const float* x     = (const float*)d_in[0];
  const float* W1l   = (const float*)d_in[1];
  const float* b1    = (const float*)d_in[2];
  const float* W1r   = (const float*)d_in[3];
  const float* W2l   = (const float*)d_in[4];
  const float* b2    = (const float*)d_in[5];
  const float* W2r   = (const float*)d_in[6];
  const int*   ei    = (const int*)d_in[7];   // [2, NE]: row0 = src, row1 = dst
  const int*   batch = (const int*)d_in[8];
  const int* esrc = ei;
  const int* edst = ei + NE;
  float* out = (float*)d_out;

  // ---- workspace carve-out (~91 MB) ----
  char* base = (char*)d_ws;
  size_t off = 0;
  auto take = [&](size_t bytes) -> char* {
    char* p = base + off;
    off += (bytes + 255) & ~(size_t)255;
    return p;
  };
  int* bbase    = (int*)take((size_t)(NBK + 1) * 4);
  int* gcur     = (int*)take((size_t)NBK * 4);
  int* offs     = (int*)take((size_t)(NN + 1) * 4);
  int* csr      = (int*)take((size_t)NE * 4);
  char* bufA    = take((size_t)NN * 256);   // xh (f16 NNx128) -> o128 (hi-cols)
  char* bufB    = take((size_t)NN * 256);   // agg1h -> [agg2h 12.8M | tq 6.4M]
  char* bufC    = take((size_t)NN * 256);   // [gpart 12.8M | xq 12.8M] -> hb
  float* pool   = (float*)take((size_t)NG * C2 * 4);  // \  one contiguous
  int*  gcnt    = (int*)take((size_t)NG * 4);         //  } memset region
  int*  ghist   = (int*)take((size_t)NBK * 4);        // /
  u16*  wt1     = (u16*)take((size_t)128 * 256 * 2);
  u16*  wt2     = (u16*)take((size_t)128 * 128 * 2);

  u16*   xh    = (u16*)bufA;
  u16*   o128  = (u16*)bufA;                // mgemm2 hi-cols (xh dead by then)
  u16*   agg1h = (u16*)bufB;
  u16*   agg2h = (u16*)bufB;                // agg1h dead after mgemm1
  u8*    tqb   = (u8*)(bufB + (size_t)NN * 128);  // fp8 t, behind agg2h
  u32*   gpart = (u32*)bufC;                // dead after bbuild
  u32*   xq    = (u32*)(bufC + (size_t)NE * 4);   // fp8 x; dead after agg1q
  u16*   hb    = (u16*)bufC;                // written by mgemm1 (gpart+xq dead)

  const size_t zbytes = (size_t)((char*)ghist + (size_t)NBK * 4 - (char*)pool);
  hipMemsetAsync(pool, 0, zbytes, stream);  // pool + gcnt + ghist

  sage_x2hw<<<(NN * 32 + 128 * 256 + 128 * 128 + 255) / 256, 256, 0, stream>>>(
      x, xh, xq, W1l, W1r, W2l, W2r, wt1, wt2);

  // CSR build
  const int PB = (NE + 4095) / 4096;        // 782 partition blocks
  sage_phist<<<PB, 256, 0, stream>>>(edst, ghist);
  sage_pscan<<<1, 256, 0, stream>>>(ghist, bbase, gcur);
  sage_part<<<PB, 256, 0, stream>>>(esrc, edst, gcur, gpart);
  sage_bbuild<<<NBK, 512, 0, stream>>>(bbase, gpart, offs, csr);

  // layer 1
  sage_agg1q<<<(NN + 3) / 4, 256, 0, stream>>>(offs, csr, xq, agg1h);
  sage_mgemm1<<<(NN + 63) / 64, 256, 0, stream>>>(agg1h, xh, wt1, b1, hb);

  // layer 2 (transform-then-aggregate: mean(h)@W2l == mean(h@W2l));
  // mgemm2: t -> tq (fp8), t2 -> o128 hi-cols (fp16)
  sage_mgemm2<<<(NN + 63) / 64, 256, 0, stream>>>(hb, wt2, o128, tqb);
  sage_agg2q<<<(NN + 3) / 4, 256, 0, stream>>>(offs, csr, (const u32*)tqb, agg2h);

  // global mean pool (node counting fused)
  sage_pool2<<<(NN + 127) / 128, 256, 0, stream>>>(o128, agg2h, b2, batch, pool, gcnt);
  sage_out<<<(NG * C2 + 255) / 256, 256, 0, stream>>>(pool, gcnt, out);
}

// Round 10
// 345.705 us; speedup vs baseline: 12.3834x; 1.0548x over previous
//
#include <hip/hip_runtime.h>

// GraphSAGE (2x SAGEConv mean + global_mean_pool) on MI355X.
// R9: (1) agg kernels reverted to R7's unmasked half/quarter-wave interleave
//     but 8 gathers in flight (R8's masked int4 windows regressed 76->84us:
//     per-edge compares ate the MLP gain). (2) phist deleted: part reserves
//     from fixed-capacity padded bucket regions (CAP=18176 ~ mean+14sigma,
//     clamp on overflow), tiny 1-block scan -> compact bbase; bbuild reads
//     padded gpart, writes compact csr/offs. (3) gcur init folded into x2hw.

constexpr int NN = 100000;    // nodes
constexpr int NE = 3200000;   // edges
constexpr int C1 = 128;       // IN_C == HID_C
constexpr int C2 = 64;        // OUT_C
constexpr int NG = 1024;      // graphs

constexpr int NBK = (NN + 511) >> 9;   // 196 buckets of 512 nodes
constexpr int CAP = 18176;             // padded edges per bucket (mean 16327)

typedef unsigned int u32;
typedef unsigned short u16;
typedef unsigned char u8;
typedef _Float16 f16;
typedef f16 f16x8 __attribute__((ext_vector_type(8)));
typedef float f32x4 __attribute__((ext_vector_type(4)));

__device__ __forceinline__ float h2f(u32 bits16) {
  f16 h; u16 b = (u16)bits16;
  __builtin_memcpy(&h, &b, 2);
  return (float)h;
}
__device__ __forceinline__ u16 f2h(float f) {
  f16 h = (f16)f; u16 b;
  __builtin_memcpy(&b, &h, 2);
  return b;
}
__device__ __forceinline__ u32 packh2(float a, float b) {
  return (u32)f2h(a) | ((u32)f2h(b) << 16);
}
// pack 4 floats -> 4 fp8 e4m3 (one u32)
__device__ __forceinline__ u32 packq4(float a, float b, float c, float d) {
  int q = 0;
  q = __builtin_amdgcn_cvt_pk_fp8_f32(a, b, q, false);
  q = __builtin_amdgcn_cvt_pk_fp8_f32(c, d, q, true);
  return (u32)q;
}
// accumulate 4 fp8 (one u32) into 4 fp32
__device__ __forceinline__ void acc4(u32 g, float& a0, float& a1,
                                     float& a2, float& a3) {
  const auto p = __builtin_amdgcn_cvt_pk_f32_fp8((int)g, false);
  const auto q = __builtin_amdgcn_cvt_pk_f32_fp8((int)g, true);
  a0 += p[0]; a1 += p[1]; a2 += q[0]; a3 += q[1];
}

// ------- fused prep: x -> fp16+fp8, weights -> fp16 [N][K], gcur init -------
__global__ __launch_bounds__(256)
void sage_x2hw(const float* __restrict__ x, u16* __restrict__ xh,
               u32* __restrict__ xq,
               const float* __restrict__ W1l, const float* __restrict__ W1r,
               const float* __restrict__ W2l, const float* __restrict__ W2r,
               u16* __restrict__ wt1, u16* __restrict__ wt2,
               int* __restrict__ gcur) {
  const int id = blockIdx.x * 256 + threadIdx.x;
  constexpr int NX = NN * 32;
  if (id < NX) {
    const float4 v = ((const float4*)x)[id];
    uint2 o;
    o.x = packh2(v.x, v.y);
    o.y = packh2(v.z, v.w);
    ((uint2*)xh)[id] = o;
    xq[id] = packq4(v.x, v.y, v.z, v.w);
  } else if (id < NX + 128 * 256) {
    const int id2 = id - NX;
    const int n = id2 >> 8, k = id2 & 255;
    const float v = (k < 128) ? W1l[k * 128 + n] : W1r[(k - 128) * 128 + n];
    wt1[id2] = f2h(v);
  } else if (id < NX + 128 * 256 + 128 * 128) {
    const int id3 = id - NX - 128 * 256;
    const int n = id3 >> 7, k = id3 & 127;
    const float v = (n < 64) ? W2l[k * 64 + n] : W2r[k * 64 + (n - 64)];
    wt2[id3] = f2h(v);
  } else if (id < NX + 128 * 256 + 128 * 128 + NBK) {
    const int b = id - NX - 128 * 256 - 128 * 128;
    gcur[b] = b * CAP;
  }
}

// ------- partition edges into padded per-bucket regions of gpart -------
// packed entry: (src<<9) | (dst&511). Per block: LDS hist -> one global
// atomicAdd per bucket -> scatter. Clamp guards the (never-hit) overflow.
__global__ __launch_bounds__(256)
void sage_part(const int* __restrict__ esrc, const int* __restrict__ edst,
               int* __restrict__ gcur, u32* __restrict__ gpart) {
  __shared__ int h[NBK], cur[NBK];
  for (int i = threadIdx.x; i < NBK; i += 256) h[i] = 0;
  __syncthreads();
  const int e0 = blockIdx.x * 4096 + threadIdx.x * 4;
#pragma unroll
  for (int j = 0; j < 4; ++j) {
    const int e = e0 + j * 1024;
    if (e < NE) {
      const int4 d = *(const int4*)(edst + e);
      atomicAdd(&h[d.x >> 9], 1);
      atomicAdd(&h[d.y >> 9], 1);
      atomicAdd(&h[d.z >> 9], 1);
      atomicAdd(&h[d.w >> 9], 1);
    }
  }
  __syncthreads();
  for (int i = threadIdx.x; i < NBK; i += 256)
    cur[i] = h[i] ? atomicAdd(&gcur[i], h[i]) : 0;
  __syncthreads();
#pragma unroll
  for (int j = 0; j < 4; ++j) {
    const int e = e0 + j * 1024;
    if (e < NE) {
      const int4 d = *(const int4*)(edst + e);
      const int4 s = *(const int4*)(esrc + e);
      int bk, p;
      bk = d.x >> 9; p = atomicAdd(&cur[bk], 1);
      if (p < (bk + 1) * CAP) gpart[p] = ((u32)s.x << 9) | (u32)(d.x & 511);
      bk = d.y >> 9; p = atomicAdd(&cur[bk], 1);
      if (p < (bk + 1) * CAP) gpart[p] = ((u32)s.y << 9) | (u32)(d.y & 511);
      bk = d.z >> 9; p = atomicAdd(&cur[bk], 1);
      if (p < (bk + 1) * CAP) gpart[p] = ((u32)s.z << 9) | (u32)(d.z & 511);
      bk = d.w >> 9; p = atomicAdd(&cur[bk], 1);
      if (p < (bk + 1) * CAP) gpart[p] = ((u32)s.w << 9) | (u32)(d.w & 511);
    }
  }
}

// ------- tiny scan: bucket counts (from gcur) -> compact bbase -------
__global__ __launch_bounds__(256)
void sage_pscan(const int* __restrict__ gcur, int* __restrict__ bbase) {
  __shared__ int s[256];
  const int t = threadIdx.x;
  int c = (t < NBK) ? (gcur[t] - t * CAP) : 0;
  c = (c > CAP) ? CAP : c;
  s[t] = c;
  __syncthreads();
  for (int d = 1; d < 256; d <<= 1) {
    const int a = (t >= d) ? s[t - d] : 0;
    __syncthreads();
    s[t] += a;
    __syncthreads();
  }
  if (t < NBK) bbase[t] = s[t] - c;
  if (t == 255) bbase[NBK] = s[255];
}

// ------- one block per bucket: padded gpart -> compact csr + offs -------
__global__ __launch_bounds__(512)
void sage_bbuild(const int* __restrict__ bbase, const u32* __restrict__ gpart,
                 int* __restrict__ offs, int* __restrict__ csr) {
  __shared__ int ldeg[512], lcur[512], ssc[512];
  const int b = blockIdx.x, t = threadIdx.x;
  const int c0 = bbase[b], cnt = bbase[b + 1] - c0;
  const u32* gp = gpart + (size_t)b * CAP;
  ldeg[t] = 0;
  __syncthreads();
  for (int e = t; e < cnt; e += 512)
    atomicAdd(&ldeg[gp[e] & 511], 1);
  __syncthreads();
  const int v = ldeg[t];
  ssc[t] = v;
  __syncthreads();
  for (int d = 1; d < 512; d <<= 1) {
    const int a = (t >= d) ? ssc[t - d] : 0;
    __syncthreads();
    ssc[t] += a;
    __syncthreads();
  }
  const int pre = ssc[t] - v;
  lcur[t] = pre;
  const int node = b * 512 + t;
  if (node < NN) offs[node] = c0 + pre;
  if (b == 0 && t == 0) offs[NN] = bbase[NBK];
  __syncthreads();
  for (int e = t; e < cnt; e += 512) {
    const u32 pk = gp[e];
    const int p = atomicAdd(&lcur[pk & 511], 1);
    csr[c0 + p] = (int)(pk >> 9);
  }
}

// ------- aggregation 1: mean of xq (fp8 [NN][128]) -> fp16 -------
// wave per node; half-wave (32 lanes x u32) covers the 128B row, halves
// interleave edges; 8 gathers in flight per lane (the latency lever).
__global__ __launch_bounds__(256)
void sage_agg1q(const int* __restrict__ offs, const int* __restrict__ csr,
                const u32* __restrict__ xq, u16* __restrict__ aggh) {
  const int node = blockIdx.x * 4 + (threadIdx.x >> 6);
  const int lane = threadIdx.x & 63;
  if (node >= NN) return;
  const int beg = offs[node], end = offs[node + 1];
  const int hf = lane >> 5, l = lane & 31;
  const u32* xb = xq + l;                             // row stride 32 u32
  float a0 = 0, a1 = 0, a2 = 0, a3 = 0;
  int e = beg + hf;
  for (; e + 14 < end; e += 16) {                     // 8 edges/half in flight
    const int i0 = csr[e],      i1 = csr[e + 2],  i2 = csr[e + 4],
              i3 = csr[e + 6],  i4 = csr[e + 8],  i5 = csr[e + 10],
              i6 = csr[e + 12], i7 = csr[e + 14];
    const u32 g0 = xb[(size_t)i0 * 32], g1 = xb[(size_t)i1 * 32],
              g2 = xb[(size_t)i2 * 32], g3 = xb[(size_t)i3 * 32],
              g4 = xb[(size_t)i4 * 32], g5 = xb[(size_t)i5 * 32],
              g6 = xb[(size_t)i6 * 32], g7 = xb[(size_t)i7 * 32];
    acc4(g0, a0, a1, a2, a3); acc4(g1, a0, a1, a2, a3);
    acc4(g2, a0, a1, a2, a3); acc4(g3, a0, a1, a2, a3);
    acc4(g4, a0, a1, a2, a3); acc4(g5, a0, a1, a2, a3);
    acc4(g6, a0, a1, a2, a3); acc4(g7, a0, a1, a2, a3);
  }
  for (; e < end; e += 2)
    acc4(xb[(size_t)csr[e] * 32], a0, a1, a2, a3);
  a0 += __shfl_xor(a0, 32);
  a1 += __shfl_xor(a1, 32);
  a2 += __shfl_xor(a2, 32);
  a3 += __shfl_xor(a3, 32);
  if (hf == 0) {
    const float inv = 1.0f / fmaxf((float)(end - beg), 1.0f);
    uint2 o;
    o.x = packh2(a0 * inv, a1 * inv);
    o.y = packh2(a2 * inv, a3 * inv);
    *(uint2*)(aggh + (size_t)node * 128 + l * 4) = o;
  }
}

// ------- aggregation 2: mean of tq (fp8 [NN][64]) -> fp16 -------
// wave per node; quarter-wave (16 lanes x u32) covers the 64B row, 4 groups
// interleave edges; 8 gathers in flight per lane.
__global__ __launch_bounds__(256)
void sage_agg2q(const int* __restrict__ offs, const int* __restrict__ csr,
                const u32* __restrict__ tq, u16* __restrict__ agg2h) {
  const int node = blockIdx.x * 4 + (threadIdx.x >> 6);
  const int lane = threadIdx.x & 63;
  if (node >= NN) return;
  const int beg = offs[node], end = offs[node + 1];
  const int grp = lane >> 4, l = lane & 15;
  const u32* tb = tq + l;                             // row stride 16 u32
  float a0 = 0, a1 = 0, a2 = 0, a3 = 0;
  int e = beg + grp;
  for (; e + 28 < end; e += 32) {                     // 8 edges/group in flight
    const int i0 = csr[e],      i1 = csr[e + 4],  i2 = csr[e + 8],
              i3 = csr[e + 12], i4 = csr[e + 16], i5 = csr[e + 20],
              i6 = csr[e + 24], i7 = csr[e + 28];
    const u32 g0 = tb[(size_t)i0 * 16], g1 = tb[(size_t)i1 * 16],
              g2 = tb[(size_t)i2 * 16], g3 = tb[(size_t)i3 * 16],
              g4 = tb[(size_t)i4 * 16], g5 = tb[(size_t)i5 * 16],
              g6 = tb[(size_t)i6 * 16], g7 = tb[(size_t)i7 * 16];
    acc4(g0, a0, a1, a2, a3); acc4(g1, a0, a1, a2, a3);
    acc4(g2, a0, a1, a2, a3); acc4(g3, a0, a1, a2, a3);
    acc4(g4, a0, a1, a2, a3); acc4(g5, a0, a1, a2, a3);
    acc4(g6, a0, a1, a2, a3); acc4(g7, a0, a1, a2, a3);
  }
  for (; e < end; e += 4)
    acc4(tb[(size_t)csr[e] * 16], a0, a1, a2, a3);
  a0 += __shfl_xor(a0, 16); a0 += __shfl_xor(a0, 32);
  a1 += __shfl_xor(a1, 16); a1 += __shfl_xor(a1, 32);
  a2 += __shfl_xor(a2, 16); a2 += __shfl_xor(a2, 32);
  a3 += __shfl_xor(a3, 16); a3 += __shfl_xor(a3, 32);
  if (lane < 16) {
    const float inv = 1.0f / fmaxf((float)(end - beg), 1.0f);
    uint2 o;
    o.x = packh2(a0 * inv, a1 * inv);
    o.y = packh2(a2 * inv, a3 * inv);
    *(uint2*)(agg2h + (size_t)node * 64 + l * 4) = o;
  }
}

// ------------- MFMA GEMM 1: H = relu(A1@W1l + A2@W1r + b1), fp16 out -------
__global__ __launch_bounds__(256)
void sage_mgemm1(const u16* __restrict__ A1, const u16* __restrict__ A2,
                 const u16* __restrict__ wt1, const float* __restrict__ bias,
                 u16* __restrict__ H) {
  __shared__ __align__(16) u16 As[2][64][128];
  const int t = threadIdx.x;
  const int r0 = blockIdx.x * 64;
#pragma unroll
  for (int i = 0; i < 8; ++i) {                       // 2048 16B-chunk loads
    const int id = i * 256 + t;
    const int buf = id >> 10;
    const int id2 = id & 1023;
    const int row = id2 >> 4, c = id2 & 15;
    int gr = r0 + row; gr = (gr < NN) ? gr : NN - 1;  // clamp; store guarded
    const uint4 v = *(const uint4*)((buf ? A2 : A1) + (size_t)gr * 128 + c * 8);
    *(uint4*)(&As[buf][row][(c ^ (row & 7)) * 8]) = v;
  }
  __syncthreads();
  const int w = t >> 6, l = t & 63;
  const int lr = l & 15, lk = l >> 4;
  const int rowl = w * 16 + lr;
  f32x4 acc[8];
#pragma unroll
  for (int c = 0; c < 8; ++c) acc[c] = (f32x4){0.f, 0.f, 0.f, 0.f};
#pragma unroll
  for (int kt = 0; kt < 8; ++kt) {                    // K = 256 in 32-steps
    const int buf = kt >> 2, kk = kt & 3;
    const int ch = (kk * 4 + lk) ^ (rowl & 7);
    const f16x8 a = *(const f16x8*)(&As[buf][rowl][ch * 8]);
#pragma unroll
    for (int c = 0; c < 8; ++c) {
      const f16x8 b = *(const f16x8*)(wt1 + ((c * 16 + lr) * 256 + kt * 32 + lk * 8));
      acc[c] = __builtin_amdgcn_mfma_f32_16x16x32_f16(a, b, acc[c], 0, 0, 0);
    }
  }
#pragma unroll
  for (int c = 0; c < 8; ++c) {                       // C/D: col=l&15, row=lk*4+j
    const int col = c * 16 + lr;
    const float bv = bias[col];
#pragma unroll
    for (int j = 0; j < 4; ++j) {
      const int row = r0 + w * 16 + lk * 4 + j;
      if (row < NN) H[(size_t)row * 128 + col] = f2h(fmaxf(acc[c][j] + bv, 0.f));
    }
  }
}

// ------------- MFMA GEMM 2: cols 0..63 (t) -> tq fp8; cols 64..127 (t2) ----
// -> o128 hi-half fp16. wt2 [128 n][128 k] fp16; no bias (b2 added in pool).
__global__ __launch_bounds__(256)
void sage_mgemm2(const u16* __restrict__ A, const u16* __restrict__ wt2,
                 u16* __restrict__ O, u8* __restrict__ tqb) {
  __shared__ __align__(16) u16 As[64][128];
  const int t = threadIdx.x;
  const int r0 = blockIdx.x * 64;
#pragma unroll
  for (int i = 0; i < 4; ++i) {
    const int id = i * 256 + t;
    const int row = id >> 4, c = id & 15;
    int gr = r0 + row; gr = (gr < NN) ? gr : NN - 1;
    const uint4 v = *(const uint4*)(A + (size_t)gr * 128 + c * 8);
    *(uint4*)(&As[row][(c ^ (row & 7)) * 8]) = v;
  }
  __syncthreads();
  const int w = t >> 6, l = t & 63;
  const int lr = l & 15, lk = l >> 4;
  const int rowl = w * 16 + lr;
  f32x4 acc[8];
#pragma unroll
  for (int c = 0; c < 8; ++c) acc[c] = (f32x4){0.f, 0.f, 0.f, 0.f};
#pragma unroll
  for (int kt = 0; kt < 4; ++kt) {                    // K = 128
    const int ch = (kt * 4 + lk) ^ (rowl & 7);
    const f16x8 a = *(const f16x8*)(&As[rowl][ch * 8]);
#pragma unroll
    for (int c = 0; c < 8; ++c) {
      const f16x8 b = *(const f16x8*)(wt2 + ((c * 16 + lr) * 128 + kt * 32 + lk * 8));
      acc[c] = __builtin_amdgcn_mfma_f32_16x16x32_f16(a, b, acc[c], 0, 0, 0);
    }
  }
#pragma unroll
  for (int c = 0; c < 8; ++c) {
    const int col = c * 16 + lr;
#pragma unroll
    for (int j = 0; j < 4; ++j) {
      const int row = r0 + w * 16 + lk * 4 + j;
      if (row < NN) {
        if (col < 64) {                               // t -> fp8 byte
          const int pk = __builtin_amdgcn_cvt_pk_fp8_f32(acc[c][j], acc[c][j], 0, false);
          tqb[(size_t)row * 64 + col] = (u8)pk;
        } else {                                      // t2 -> o128 hi fp16
          O[(size_t)row * 128 + col] = f2h(acc[c][j]);
        }
      }
    }
  }
}

// ------------- pooling (fused node counting, sorted-batch runs) -------------
__global__ __launch_bounds__(256)
void sage_pool2(const u16* __restrict__ o128, const u16* __restrict__ agg2h,
                const float* __restrict__ b2, const int* __restrict__ batch,
                float* __restrict__ pool, int* __restrict__ gcnt) {
  const int t = threadIdx.x;
  const int c = t & 63, sl = t >> 6;
  const int n0 = blockIdx.x * 128;
  const float bv = b2[c];
  float acc = 0.f;
  int curg = -1, cnt = 0;
  for (int n = n0 + sl; n < n0 + 128 && n < NN; n += 4) {
    const int g = batch[n];
    const float v = h2f(o128[(size_t)n * 128 + 64 + c]) +
                    h2f(agg2h[(size_t)n * 64 + c]) + bv;
    if (g != curg) {
      if (curg >= 0) {
        atomicAdd(&pool[curg * C2 + c], acc);
        if (c == 0) atomicAdd(&gcnt[curg], cnt);
      }
      curg = g; acc = v; cnt = 1;
    } else {
      acc += v; cnt += 1;
    }
  }
  if (curg >= 0) {
    atomicAdd(&pool[curg * C2 + c], acc);
    if (c == 0) atomicAdd(&gcnt[curg], cnt);
  }
}

__global__ __launch_bounds__(256)
void sage_out(const float* __restrict__ pool, const int* __restrict__ gcnt,
              float* __restrict__ out) {
  const int i = blockIdx.x * 256 + threadIdx.x;
  if (i >= NG * C2) return;
  out[i] = pool[i] / fmaxf((float)gcnt[i >> 6], 1.0f);
}

extern "C" void kernel_launch(void* const* d_in, const int* in_sizes, int n_in,
                              void* d_out, int out_size, void* d_ws, size_t ws_size,
                              hipStream_t stream) {
  (void)in_sizes; (void)n_in; (void)out_size; (void)ws_size;
  const float* x     = (const float*)d_in[0];
  const float* W1l   = (const float*)d_in[1];
  const float* b1    = (const float*)d_in[2];
  const float* W1r   = (const float*)d_in[3];
  const float* W2l   = (const float*)d_in[4];
  const float* b2    = (const float*)d_in[5];
  const float* W2r   = (const float*)d_in[6];
  const int*   ei    = (const int*)d_in[7];   // [2, NE]: row0 = src, row1 = dst
  const int*   batch = (const int*)d_in[8];
  const int* esrc = ei;
  const int* edst = ei + NE;
  float* out = (float*)d_out;

  // ---- workspace carve-out (~92 MB) ----
  char* base = (char*)d_ws;
  size_t off = 0;
  auto take = [&](size_t bytes) -> char* {
    char* p = base + off;
    off += (bytes + 255) & ~(size_t)255;
    return p;
  };
  int* bbase    = (int*)take((size_t)(NBK + 1) * 4);
  int* gcur     = (int*)take((size_t)NBK * 4);
  int* offs     = (int*)take((size_t)(NN + 1) * 4);
  int* csr      = (int*)take((size_t)NE * 4);
  char* bufA    = take((size_t)NN * 256);   // xh (f16 NNx128) -> o128 (hi-cols)
  char* bufB    = take((size_t)NN * 256);   // agg1h -> [agg2h 12.8M | tq 6.4M]
  char* bufC    = take((size_t)NBK * CAP * 4 + (size_t)NN * 128);
                                            // [gpart padded 14.25M | xq 12.8M] -> hb
  float* pool   = (float*)take((size_t)NG * C2 * 4);  // \ one contiguous
  int*  gcnt    = (int*)take((size_t)NG * 4);         // / memset region
  u16*  wt1     = (u16*)take((size_t)128 * 256 * 2);
  u16*  wt2     = (u16*)take((size_t)128 * 128 * 2);

  u16*   xh    = (u16*)bufA;
  u16*   o128  = (u16*)bufA;                // mgemm2 hi-cols (xh dead by then)
  u16*   agg1h = (u16*)bufB;
  u16*   agg2h = (u16*)bufB;                // agg1h dead after mgemm1
  u8*    tqb   = (u8*)(bufB + (size_t)NN * 128);  // fp8 t, behind agg2h
  u32*   gpart = (u32*)bufC;                // padded; dead after bbuild
  u32*   xq    = (u32*)(bufC + (size_t)NBK * CAP * 4);  // fp8 x; dead after agg1q
  u16*   hb    = (u16*)bufC;                // written by mgemm1 (gpart+xq dead)

  const size_t zbytes = (size_t)((char*)gcnt + (size_t)NG * 4 - (char*)pool);
  hipMemsetAsync(pool, 0, zbytes, stream);  // pool + gcnt

  sage_x2hw<<<(NN * 32 + 128 * 256 + 128 * 128 + NBK + 255) / 256, 256, 0,
              stream>>>(x, xh, xq, W1l, W1r, W2l, W2r, wt1, wt2, gcur);

  // CSR build (fixed-capacity partition; no global histogram pass)
  const int PB = (NE + 4095) / 4096;        // 782 partition blocks
  sage_part<<<PB, 256, 0, stream>>>(esrc, edst, gcur, gpart);
  sage_pscan<<<1, 256, 0, stream>>>(gcur, bbase);
  sage_bbuild<<<NBK, 512, 0, stream>>>(bbase, gpart, offs, csr);

  // layer 1
  sage_agg1q<<<(NN + 3) / 4, 256, 0, stream>>>(offs, csr, xq, agg1h);
  sage_mgemm1<<<(NN + 63) / 64, 256, 0, stream>>>(agg1h, xh, wt1, b1, hb);

  // layer 2 (transform-then-aggregate: mean(h)@W2l == mean(h@W2l));
  // mgemm2: t -> tq (fp8), t2 -> o128 hi-cols (fp16)
  sage_mgemm2<<<(NN + 63) / 64, 256, 0, stream>>>(hb, wt2, o128, tqb);
  sage_agg2q<<<(NN + 3) / 4, 256, 0, stream>>>(offs, csr, (const u32*)tqb, agg2h);

  // global mean pool (node counting fused)
  sage_pool2<<<(NN + 127) / 128, 256, 0, stream>>>(o128, agg2h, b2, batch, pool, gcnt);
  sage_out<<<(NG * C2 + 255) / 256, 256, 0, stream>>>(pool, gcnt, out);
}